// Round 8
// baseline (283.723 us; speedup 1.0000x reference)
//
#include <hip/hip_runtime.h>
#include <stdint.h>

// TBN BasicBlock on MI355X, round 8: zero-VALU tap loop, K=32 dbuf chunks.
//   out = x + conv3x3(sign(bn2(conv3x3(sign(bn1(x)), tern(w1)))), tern(w2))
// Conv: BM=512 px (16 rows) x BN=64 cout, 8 waves (512 thr), wave tile 64x64
// via mfma_i32_32x32x32_i8. K-loop = 8 ci-chunks of 32. All tap LDS addresses
// precomputed into VGPRs (halo select baked in); tap-dependent offsets are
// compile-time immediates -> tap loop is pure {4 ds_read_b128 -> 4 MFMA},
// 2-deep software-pipelined (tap t+1 reads issue before tap t MFMAs).
// A+B double-buffered (73792 B LDS); chunk c+1 staged at top of chunk c;
// one barrier per chunk drains ~300-cycle-old global_load_lds.

#define EPS 1e-5f

typedef int i32x4  __attribute__((ext_vector_type(4)));
typedef int i32x16 __attribute__((ext_vector_type(16)));

__device__ __forceinline__ void gload16(const void* g, void* l) {
  __builtin_amdgcn_global_load_lds(
      (const __attribute__((address_space(1))) void*)g,
      (__attribute__((address_space(3))) void*)l, 16, 0, 0);
}

// ---------------- stage 1: sum |w| for both weights (grid 72x2) -------------
__global__ __launch_bounds__(256) void wsum_kernel(const float* __restrict__ w1,
                                                   const float* __restrict__ w2,
                                                   float* __restrict__ partial) {
  __shared__ float red[256];
  const int t = threadIdx.x;
  const int b = blockIdx.x;
  const float* w = blockIdx.y ? w2 : w1;
  float s = 0.f;
#pragma unroll
  for (int i = 0; i < 32; ++i) s += fabsf(w[b * 256 + t + i * 18432]);
  red[t] = s;
  __syncthreads();
  for (int o = 128; o > 0; o >>= 1) {
    if (t < o) red[t] += red[t + o];
    __syncthreads();
  }
  if (t == 0) partial[(blockIdx.y << 7) + b] = red[0];
}

__global__ void delta_kernel(const float* __restrict__ p1, const float* __restrict__ p2,
                             float* __restrict__ delta) {
  const int t = threadIdx.x;
  if (t < 2) {
    const float* p = (t == 0) ? p1 : p2;
    double s = 0.0;
    for (int i = 0; i < 72; ++i) s += (double)p[i];
    delta[t] = 0.7f * (float)(s * (1.0 / 589824.0));
  }
}

// ------------- stage 2: quantize both weights (grid 2304x2) -----------------
// Layout matches conv LDS staging: nb=co>>6, chunk=ci>>5, slot=(ci&31)>>4
//   off = nb*147456 + chunk*18432 + tap*2048 + slot*1024 + (co&63)*16 + (ci&15)
__global__ __launch_bounds__(256) void quant_kernel(const float* __restrict__ w1,
                                                    const float* __restrict__ w2,
                                                    const float* __restrict__ delta2,
                                                    int8_t* __restrict__ wq1,
                                                    int8_t* __restrict__ wq2,
                                                    float* __restrict__ psbase) {
  __shared__ float rs[256];
  __shared__ float rc[256];
  const int t = threadIdx.x;
  const int by = blockIdx.y;
  const float* w = by ? w2 : w1;
  int8_t* wq = by ? wq2 : wq1;
  const int idx = blockIdx.x * 256 + t;
  const float d = delta2[by];
  const float v = w[idx];
  const float av = fabsf(v);
  const bool m = av > d;
  const int co = idx / 2304;
  const int rem = idx - co * 2304;
  const int ci = rem / 9;
  const int tap = rem - ci * 9;
  wq[(co >> 6) * 147456 + (ci >> 5) * 18432 + tap * 2048 +
     (((ci & 31) >> 4) << 10) + ((co & 63) << 4) + (ci & 15)] =
      m ? (v > 0.f ? (int8_t)1 : (int8_t)-1) : (int8_t)0;
  rs[t] = m ? av : 0.f;
  rc[t] = m ? 1.f : 0.f;
  __syncthreads();
  for (int o = 128; o > 0; o >>= 1) {
    if (t < o) { rs[t] += rs[t + o]; rc[t] += rc[t + o]; }
    __syncthreads();
  }
  if (t == 0) { psbase[by * 4608 + blockIdx.x] = rs[0];
                psbase[by * 4608 + 2304 + blockIdx.x] = rc[0]; }
}

__global__ __launch_bounds__(256) void alpha_kernel(const float* __restrict__ ps1, const float* __restrict__ pc1,
                                                    const float* __restrict__ ps2, const float* __restrict__ pc2,
                                                    const float* __restrict__ g2, const float* __restrict__ b2,
                                                    const float* __restrict__ m2, const float* __restrict__ v2,
                                                    float* __restrict__ alphas,
                                                    float* __restrict__ inv2o, float* __restrict__ add2o) {
  __shared__ float rs[256];
  __shared__ float rc[256];
  const int t = threadIdx.x;
  float s1 = 0.f, c1 = 0.f, s2 = 0.f, c2 = 0.f;
#pragma unroll
  for (int i = 0; i < 9; ++i) {
    s1 += ps1[t + (i << 8)]; c1 += pc1[t + (i << 8)];
    s2 += ps2[t + (i << 8)]; c2 += pc2[t + (i << 8)];
  }
  rs[t] = s1; rc[t] = c1;
  __syncthreads();
  for (int o = 128; o > 0; o >>= 1) {
    if (t < o) { rs[t] += rs[t + o]; rc[t] += rc[t + o]; }
    __syncthreads();
  }
  if (t == 0) alphas[0] = rs[0] / fmaxf(rc[0], 1.f);
  __syncthreads();
  rs[t] = s2; rc[t] = c2;
  __syncthreads();
  for (int o = 128; o > 0; o >>= 1) {
    if (t < o) { rs[t] += rs[t + o]; rc[t] += rc[t + o]; }
    __syncthreads();
  }
  if (t == 0) alphas[1] = rs[0] / fmaxf(rc[0], 1.f);
  const float inv = g2[t] * rsqrtf(v2[t] + EPS);
  inv2o[t] = inv;
  add2o[t] = b2[t] - m2[t] * inv;
}

// -------- stage 3: bn1 + binarize + NCHW -> NHWC (+-1 int8) -----------------
__global__ __launch_bounds__(256) void bn_bin_kernel(const float* __restrict__ x,
                                                     const float* __restrict__ g1,
                                                     const float* __restrict__ b1,
                                                     const float* __restrict__ m1,
                                                     const float* __restrict__ v1,
                                                     int8_t* __restrict__ a1) {
  __shared__ int8_t lds[64 * 40];
  const int t = threadIdx.x;
  const int p0 = blockIdx.x << 6;
  const int c0 = blockIdx.y << 5;
  const int n = blockIdx.z;
  const int pl = t & 63;
  const int cl0 = t >> 6;
#pragma unroll
  for (int i = 0; i < 8; ++i) {
    const int cl = cl0 + (i << 2);
    const int c = c0 + cl;
    const float inv = g1[c] * rsqrtf(v1[c] + EPS);
    const float ad = b1[c] - m1[c] * inv;
    const float val = x[(((n << 8) + c) << 10) + p0 + pl];
    const float tt = fmaf(val, inv, ad);
    lds[pl * 40 + cl] = (tt >= 0.f) ? (int8_t)1 : (int8_t)-1;
  }
  __syncthreads();
  const int pl2 = t >> 2;
  const int s2 = (t & 3) << 3;
  const uint2 o = *(const uint2*)&lds[pl2 * 40 + s2];
  *(uint2*)&a1[(((n << 10) + p0 + pl2) << 8) + c0 + s2] = o;
}

// -------- stages 4/5: pipelined implicit-GEMM conv3x3 (i8 32x32 MFMA) -------
struct Frag { i32x4 a0, a1, b0, b1; };

#define LOADF(F, TAP, AR, BR) do {                                          \
  F.a0 = *(const i32x4*)((AR) + aOff0[TAP]);                                \
  F.a1 = *(const i32x4*)((AR) + aOff1[TAP]);                                \
  F.b0 = *(const i32x4*)((BR) + bOff + (TAP) * 2048);                       \
  F.b1 = *(const i32x4*)((BR) + bOff + (TAP) * 2048 + 512);                 \
} while (0)

#define MMAF(F) do {                                                        \
  __builtin_amdgcn_s_setprio(1);                                            \
  acc00 = __builtin_amdgcn_mfma_i32_32x32x32_i8(F.a0, F.b0, acc00, 0, 0, 0);\
  acc01 = __builtin_amdgcn_mfma_i32_32x32x32_i8(F.a0, F.b1, acc01, 0, 0, 0);\
  acc10 = __builtin_amdgcn_mfma_i32_32x32x32_i8(F.a1, F.b0, acc10, 0, 0, 0);\
  acc11 = __builtin_amdgcn_mfma_i32_32x32x32_i8(F.a1, F.b1, acc11, 0, 0, 0);\
  __builtin_amdgcn_s_setprio(0);                                            \
} while (0)

#define STAGE(CH, AW, BW) do {                                              \
  const int8_t* wch = wnb + (CH) * 18432;                                   \
  _Pragma("unroll")                                                         \
  for (int i = 0; i < 5; ++i) {                                             \
    if (i < 4 || tid < 256) {                                               \
      if (stA[i]) gload16(act + sOff[i] + ((CH) << 5), (AW) + dOff[i]);     \
      else        gload16(wch + sOff[i], (BW) + dOff[i]);                   \
    }                                                                       \
  }                                                                         \
} while (0)

#define CHUNK(CH, AR, BR, AW, BW, DOSTAGE) do {                             \
  if (DOSTAGE) STAGE((CH) + 1, AW, BW);                                     \
  Frag fa, fb;                                                              \
  LOADF(fa, 0, AR, BR); LOADF(fb, 1, AR, BR);                               \
  MMAF(fa);                                                                 \
  LOADF(fa, 2, AR, BR); MMAF(fb);                                           \
  LOADF(fb, 3, AR, BR); MMAF(fa);                                           \
  LOADF(fa, 4, AR, BR); MMAF(fb);                                           \
  LOADF(fb, 5, AR, BR); MMAF(fa);                                           \
  LOADF(fa, 6, AR, BR); MMAF(fb);                                           \
  LOADF(fb, 7, AR, BR); MMAF(fa);                                           \
  LOADF(fa, 8, AR, BR); MMAF(fb);                                           \
  MMAF(fa);                                                                 \
} while (0)

template <int EPI>
__global__ __launch_bounds__(512, 2) void conv3x3_tbn(
    const int8_t* __restrict__ act,   // NHWC int8 [B*1024][256]
    const int8_t* __restrict__ wq,    // [nb4][chunk8][tap9][slot2][co64][16]
    const float* __restrict__ alphas, const int aidx,
    const float* __restrict__ inv2, const float* __restrict__ add2,  // EPI==0
    const float* __restrict__ xres,                                  // EPI==1
    int8_t* __restrict__ aout, float* __restrict__ fout) {
  __shared__ int8_t ldsA0[2 * 577 * 16];   // [slot2][px576 + zero][16]; 18464
  __shared__ int8_t ldsA1[2 * 577 * 16];
  __shared__ int8_t ldsB0[9 * 2 * 64 * 16];  // [tap][slot2][co64][16]; 18432
  __shared__ int8_t ldsB1[9 * 2 * 64 * 16];

  const int tid = threadIdx.x;
  const int bid = blockIdx.x;
  const int L = (bid & 7) * 64 + (bid >> 3);  // XCD swizzle, 512 blocks
  const int mb = L >> 2;            // 128 pixel tiles (16 image rows each)
  const int nb = L & 3;             // cout quarter
  const int n = mb >> 1;
  const int y0 = (mb & 1) << 4;
  const int l = tid & 63;
  const int wid = tid >> 6;         // 8 waves, 2 image rows each
  const int lx = l & 31;
  const int lh = l >> 5;

  // ---- precomputed tap-loop addresses (zero VALU inside the loop) ----
  int aOff0[9], aOff1[9];
#pragma unroll
  for (int tap = 0; tap < 9; ++tap) {
    const int ky = tap / 3, kx = tap % 3;
    const int xs = lx + kx - 1;
    const bool xok = (unsigned)xs < 32u;
#pragma unroll
    for (int mt = 0; mt < 2; ++mt) {
      const int yr = (wid << 1) + mt + ky;
      const bool ok = xok && ((unsigned)(y0 - 1 + yr) < 32u);
      const int apix = ok ? (yr << 5) + xs : 576;  // 576 = zero-px
      const int off = lh * 9232 + (apix << 4);
      if (mt == 0) aOff0[tap] = off; else aOff1[tap] = off;
    }
  }
  const int bOff = (lh << 10) + (lx << 4);

  // ---- staging plan: 2304 16B-granules = A[0,1152) + B[1152,2304) ----
  bool stA[5];
  int sOff[5], dOff[5];
#pragma unroll
  for (int i = 0; i < 5; ++i) {
    const int idx = tid + (i << 9);
    if (idx < 1152) {
      stA[i] = true;
      const int sl = idx / 576;
      const int px = idx - sl * 576;
      int ys = y0 - 1 + (px >> 5);
      ys = ys < 0 ? 0 : (ys > 31 ? 31 : ys);  // clamp; OOB rows only via zero-px
      sOff[i] = (((n << 10) + (ys << 5) + (px & 31)) << 8) + (sl << 4);
      dOff[i] = sl * 9232 + (px << 4);
    } else {
      stA[i] = false;
      const int j = idx - 1152;
      sOff[i] = j << 4;
      dOff[i] = j << 4;
    }
  }

  i32x16 acc00 = (i32x16)(0), acc01 = (i32x16)(0);
  i32x16 acc10 = (i32x16)(0), acc11 = (i32x16)(0);

  const int8_t* wnb = wq + nb * 147456;

  // zero-px (index 576) in both A buffers, both slots
  if (tid < 4) {
    int8_t* zb = (tid & 2) ? ldsA1 : ldsA0;
    *(i32x4*)(zb + (tid & 1) * 9232 + 9216) = (i32x4){0, 0, 0, 0};
  }

  STAGE(0, ldsA0, ldsB0);
  __syncthreads();

  CHUNK(0, ldsA0, ldsB0, ldsA1, ldsB1, true);  __syncthreads();
  CHUNK(1, ldsA1, ldsB1, ldsA0, ldsB0, true);  __syncthreads();
  CHUNK(2, ldsA0, ldsB0, ldsA1, ldsB1, true);  __syncthreads();
  CHUNK(3, ldsA1, ldsB1, ldsA0, ldsB0, true);  __syncthreads();
  CHUNK(4, ldsA0, ldsB0, ldsA1, ldsB1, true);  __syncthreads();
  CHUNK(5, ldsA1, ldsB1, ldsA0, ldsB0, true);  __syncthreads();
  CHUNK(6, ldsA0, ldsB0, ldsA1, ldsB1, true);  __syncthreads();
  CHUNK(7, ldsA1, ldsB1, ldsA0, ldsB0, false);

  // C/D (32x32): n(co) = lane&31, m(px) = (reg&3) + 8*(reg>>2) + 4*(lane>>5)
  const float alpha = alphas[aidx];
  if constexpr (EPI == 0) {
#define EPI0(ACC, MT, NT) {                                                  \
    const int co = (nb << 6) + ((NT) << 5) + lx;                             \
    const float inv = inv2[co];                                              \
    const float ad = add2[co];                                               \
    const int pixbase = (mb << 9) + (((wid << 1) + (MT)) << 5) + (lh << 2);  \
    _Pragma("unroll")                                                        \
    for (int rg = 0; rg < 16; ++rg) {                                        \
      const int pix = pixbase + (rg & 3) + ((rg >> 2) << 3);                 \
      const float h = alpha * (float)ACC[rg];                                \
      const float tt = fmaf(h, inv, ad);                                     \
      aout[(pix << 8) + co] = (tt >= 0.f) ? (int8_t)1 : (int8_t)-1;          \
    } }
    EPI0(acc00, 0, 0); EPI0(acc01, 0, 1); EPI0(acc10, 1, 0); EPI0(acc11, 1, 1);
  } else {
#define EPI1(ACC, MT, NT) {                                                  \
    const int co = (nb << 6) + ((NT) << 5) + lx;                             \
    const int pimg0 = ((mb & 1) << 9) + (((wid << 1) + (MT)) << 5) + (lh << 2); \
    _Pragma("unroll")                                                        \
    for (int qd = 0; qd < 4; ++qd) {                                         \
      const int off = (((n << 8) + co) << 10) + pimg0 + (qd << 3);           \
      const float4 xv = *(const float4*)(xres + off);                        \
      float4 o;                                                              \
      o.x = xv.x + alpha * (float)ACC[qd * 4 + 0];                           \
      o.y = xv.y + alpha * (float)ACC[qd * 4 + 1];                           \
      o.z = xv.z + alpha * (float)ACC[qd * 4 + 2];                           \
      o.w = xv.w + alpha * (float)ACC[qd * 4 + 3];                           \
      *(float4*)(fout + off) = o;                                            \
    } }
    EPI1(acc00, 0, 0); EPI1(acc01, 0, 1); EPI1(acc10, 1, 0); EPI1(acc11, 1, 1);
  }
}

extern "C" void kernel_launch(void* const* d_in, const int* in_sizes, int n_in,
                              void* d_out, int out_size, void* d_ws, size_t ws_size,
                              hipStream_t stream) {
  const float* x  = (const float*)d_in[0];
  const float* g1 = (const float*)d_in[1];
  const float* b1 = (const float*)d_in[2];
  const float* m1 = (const float*)d_in[3];
  const float* v1 = (const float*)d_in[4];
  const float* w1 = (const float*)d_in[5];
  const float* g2 = (const float*)d_in[6];
  const float* b2 = (const float*)d_in[7];
  const float* m2 = (const float*)d_in[8];
  const float* v2 = (const float*)d_in[9];
  const float* w2 = (const float*)d_in[10];
  float* out = (float*)d_out;

  char* ws = (char*)d_ws;
  int8_t* a1  = (int8_t*)(ws);                       // 16 MB
  int8_t* a2  = (int8_t*)(ws + 16777216);            // 16 MB
  int8_t* wq1 = (int8_t*)(ws + 33554432);            // 576 KB
  int8_t* wq2 = (int8_t*)(ws + 33554432 + 589824);   // 576 KB
  float* fs = (float*)(ws + 33554432 + 1179648);
  float* pd1    = fs;          // 72 entries
  float* pd2    = fs + 128;    // 72 entries
  float* deltas = fs + 256;
  float* alphas = fs + 260;
  float* psb    = fs + 512;    // ps1[2304], pc1[2304], ps2[2304], pc2[2304]
  float* inv2   = fs + 512 + 9216;
  float* add2   = fs + 512 + 9472;

  hipLaunchKernelGGL(wsum_kernel, dim3(72, 2), dim3(256), 0, stream, w1, w2, fs);
  hipLaunchKernelGGL(delta_kernel, dim3(1), dim3(64), 0, stream, pd1, pd2, deltas);
  hipLaunchKernelGGL(quant_kernel, dim3(2304, 2), dim3(256), 0, stream,
                     w1, w2, deltas, wq1, wq2, psb);
  hipLaunchKernelGGL(alpha_kernel, dim3(1), dim3(256), 0, stream,
                     psb, psb + 2304, psb + 4608, psb + 6912,
                     g2, b2, m2, v2, alphas, inv2, add2);
  hipLaunchKernelGGL(bn_bin_kernel, dim3(16, 8, 64), dim3(256), 0, stream, x, g1, b1, m1, v1, a1);
  hipLaunchKernelGGL((conv3x3_tbn<0>), dim3(512), dim3(512), 0, stream,
                     a1, wq1, alphas, 0, inv2, add2, (const float*)nullptr,
                     a2, (float*)nullptr);
  hipLaunchKernelGGL((conv3x3_tbn<1>), dim3(512), dim3(512), 0, stream,
                     a2, wq2, alphas, 1, (const float*)nullptr, (const float*)nullptr, x,
                     (int8_t*)nullptr, out);
  (void)in_sizes; (void)n_in; (void)out_size; (void)ws_size;
}

// Round 9
// 136.895 us; speedup vs baseline: 2.0726x; 2.0726x over previous
//
#include <hip/hip_runtime.h>
#include <stdint.h>

// TBN BasicBlock on MI355X, round 9: int8, 16x16x64 MFMA (K=64/instr),
// read:MFMA ratio 0.5, r6's proven 2-blocks/CU schedule.
//   out = x + conv3x3(sign(bn2(conv3x3(sign(bn1(x)), tern(w1)))), tern(w2))
// Conv: BM=512 px (16 rows) x BN=64 cout, 8 waves (512 thr), wave tile 64x64
// = 4m x 4n 16x16 tiles. Per tap: 4 A + 4 B ds_read_b128 feed 16 MFMAs.
// K-loop = 4 ci-chunks of 64; per chunk all nine tap B-panels LDS-resident.
// LDS: A [slot4][577px][16B]=36928 (577 stride = conflict-free shift)
//    + B [tap9][slot4][co65][16B]=37440 (65 pad kills 4-way conflict)
//    = 74368 B -> 2 blocks/CU, 16 waves/CU. 2 barriers/chunk (r6 schedule).

#define EPS 1e-5f

typedef int i32x4 __attribute__((ext_vector_type(4)));

__device__ __forceinline__ void gload16(const void* g, void* l) {
  __builtin_amdgcn_global_load_lds(
      (const __attribute__((address_space(1))) void*)g,
      (__attribute__((address_space(3))) void*)l, 16, 0, 0);
}

// ---------------- stage 1: sum |w| for both weights (grid 72x2) -------------
__global__ __launch_bounds__(256) void wsum_kernel(const float* __restrict__ w1,
                                                   const float* __restrict__ w2,
                                                   float* __restrict__ partial) {
  __shared__ float red[256];
  const int t = threadIdx.x;
  const int b = blockIdx.x;
  const float* w = blockIdx.y ? w2 : w1;
  float s = 0.f;
#pragma unroll
  for (int i = 0; i < 32; ++i) s += fabsf(w[b * 256 + t + i * 18432]);
  red[t] = s;
  __syncthreads();
  for (int o = 128; o > 0; o >>= 1) {
    if (t < o) red[t] += red[t + o];
    __syncthreads();
  }
  if (t == 0) partial[(blockIdx.y << 7) + b] = red[0];
}

__global__ void delta_kernel(const float* __restrict__ p1, const float* __restrict__ p2,
                             float* __restrict__ delta) {
  const int t = threadIdx.x;
  if (t < 2) {
    const float* p = (t == 0) ? p1 : p2;
    double s = 0.0;
    for (int i = 0; i < 72; ++i) s += (double)p[i];
    delta[t] = 0.7f * (float)(s * (1.0 / 589824.0));
  }
}

// ------------- stage 2: quantize both weights (grid 2304x2) -----------------
// Global layout == conv LDS layout (staged linearly):
//   nb=co>>6, chunk=ci>>6, slot=(ci&63)>>4, b=ci&15, col=co&63
//   off = nb*149760 + chunk*37440 + (tap*260 + slot*65 + col)*16 + b
__global__ __launch_bounds__(256) void quant_kernel(const float* __restrict__ w1,
                                                    const float* __restrict__ w2,
                                                    const float* __restrict__ delta2,
                                                    int8_t* __restrict__ wq1,
                                                    int8_t* __restrict__ wq2,
                                                    float* __restrict__ psbase) {
  __shared__ float rs[256];
  __shared__ float rc[256];
  const int t = threadIdx.x;
  const int by = blockIdx.y;
  const float* w = by ? w2 : w1;
  int8_t* wq = by ? wq2 : wq1;
  const int idx = blockIdx.x * 256 + t;
  const float d = delta2[by];
  const float v = w[idx];
  const float av = fabsf(v);
  const bool m = av > d;
  const int co = idx / 2304;
  const int rem = idx - co * 2304;
  const int ci = rem / 9;
  const int tap = rem - ci * 9;
  wq[(co >> 6) * 149760 + (ci >> 6) * 37440 +
     (tap * 260 + (((ci & 63) >> 4) * 65) + (co & 63)) * 16 + (ci & 15)] =
      m ? (v > 0.f ? (int8_t)1 : (int8_t)-1) : (int8_t)0;
  rs[t] = m ? av : 0.f;
  rc[t] = m ? 1.f : 0.f;
  __syncthreads();
  for (int o = 128; o > 0; o >>= 1) {
    if (t < o) { rs[t] += rs[t + o]; rc[t] += rc[t + o]; }
    __syncthreads();
  }
  if (t == 0) { psbase[by * 4608 + blockIdx.x] = rs[0];
                psbase[by * 4608 + 2304 + blockIdx.x] = rc[0]; }
}

__global__ __launch_bounds__(256) void alpha_kernel(const float* __restrict__ ps1, const float* __restrict__ pc1,
                                                    const float* __restrict__ ps2, const float* __restrict__ pc2,
                                                    const float* __restrict__ g2, const float* __restrict__ b2,
                                                    const float* __restrict__ m2, const float* __restrict__ v2,
                                                    float* __restrict__ alphas,
                                                    float* __restrict__ inv2o, float* __restrict__ add2o) {
  __shared__ float rs[256];
  __shared__ float rc[256];
  const int t = threadIdx.x;
  float s1 = 0.f, c1 = 0.f, s2 = 0.f, c2 = 0.f;
#pragma unroll
  for (int i = 0; i < 9; ++i) {
    s1 += ps1[t + (i << 8)]; c1 += pc1[t + (i << 8)];
    s2 += ps2[t + (i << 8)]; c2 += pc2[t + (i << 8)];
  }
  rs[t] = s1; rc[t] = c1;
  __syncthreads();
  for (int o = 128; o > 0; o >>= 1) {
    if (t < o) { rs[t] += rs[t + o]; rc[t] += rc[t + o]; }
    __syncthreads();
  }
  if (t == 0) alphas[0] = rs[0] / fmaxf(rc[0], 1.f);
  __syncthreads();
  rs[t] = s2; rc[t] = c2;
  __syncthreads();
  for (int o = 128; o > 0; o >>= 1) {
    if (t < o) { rs[t] += rs[t + o]; rc[t] += rc[t + o]; }
    __syncthreads();
  }
  if (t == 0) alphas[1] = rs[0] / fmaxf(rc[0], 1.f);
  const float inv = g2[t] * rsqrtf(v2[t] + EPS);
  inv2o[t] = inv;
  add2o[t] = b2[t] - m2[t] * inv;
}

// -------- stage 3: bn1 + binarize + NCHW -> NHWC (+-1 int8) -----------------
__global__ __launch_bounds__(256) void bn_bin_kernel(const float* __restrict__ x,
                                                     const float* __restrict__ g1,
                                                     const float* __restrict__ b1,
                                                     const float* __restrict__ m1,
                                                     const float* __restrict__ v1,
                                                     int8_t* __restrict__ a1) {
  __shared__ int8_t lds[64 * 40];
  const int t = threadIdx.x;
  const int p0 = blockIdx.x << 6;
  const int c0 = blockIdx.y << 5;
  const int n = blockIdx.z;
  const int pl = t & 63;
  const int cl0 = t >> 6;
#pragma unroll
  for (int i = 0; i < 8; ++i) {
    const int cl = cl0 + (i << 2);
    const int c = c0 + cl;
    const float inv = g1[c] * rsqrtf(v1[c] + EPS);
    const float ad = b1[c] - m1[c] * inv;
    const float val = x[(((n << 8) + c) << 10) + p0 + pl];
    const float tt = fmaf(val, inv, ad);
    lds[pl * 40 + cl] = (tt >= 0.f) ? (int8_t)1 : (int8_t)-1;
  }
  __syncthreads();
  const int pl2 = t >> 2;
  const int s2 = (t & 3) << 3;
  const uint2 o = *(const uint2*)&lds[pl2 * 40 + s2];
  *(uint2*)&a1[(((n << 10) + p0 + pl2) << 8) + c0 + s2] = o;
}

// -------- stages 4/5: per-chunk implicit-GEMM conv3x3 (i8 16x16x64) ---------
template <int EPI>
__global__ __launch_bounds__(512, 2) void conv3x3_tbn(
    const int8_t* __restrict__ act,   // NHWC int8 [B*1024][256]
    const int8_t* __restrict__ wq,    // [nb4][chunk4][tap9 x slot4 x co65][16]
    const float* __restrict__ alphas, const int aidx,
    const float* __restrict__ inv2, const float* __restrict__ add2,  // EPI==0
    const float* __restrict__ xres,                                  // EPI==1
    int8_t* __restrict__ aout, float* __restrict__ fout) {
  __shared__ int8_t ldsA[4 * 577 * 16];   // [slot][px 576 + zero][16]; 36928
  __shared__ int8_t ldsB[2340 * 16];      // [tap][slot][co 65][16];    37440

  const int tid = threadIdx.x;
  const int bid = blockIdx.x;
  const int L = (bid & 7) * 64 + (bid >> 3);  // XCD swizzle, 512 blocks
  const int mb = L >> 2;            // 128 pixel tiles (16 image rows each)
  const int nb = L & 3;             // cout quarter
  const int n = mb >> 1;
  const int y0 = (mb & 1) << 4;
  const int l = tid & 63;
  const int wid = tid >> 6;         // 8 waves, 2 image rows each
  const int c = l & 15;             // M-row / N-col lane index
  const int kq = l >> 4;            // K-quarter

  // ---- A staging: 2304 granules = [slot 4][px 576], 16B each ----
  int srcA[5], dstA[5];
#pragma unroll
  for (int i = 0; i < 5; ++i) {
    const int idx = tid + (i << 9);
    const int sl = idx / 576;
    const int px = idx - sl * 576;
    int ys = y0 - 1 + (px >> 5);
    ys = ys < 0 ? 0 : (ys > 31 ? 31 : ys);  // clamp; OOB rows only via zero-px
    srcA[i] = (((n << 10) + (ys << 5) + (px & 31)) << 8) + (sl << 4);
    dstA[i] = sl * 9232 + (px << 4);
  }
  // zero-px (index 576) in each slot region — never overwritten
  if (tid < 4) *(i32x4*)(ldsA + tid * 9232 + 9216) = (i32x4){0, 0, 0, 0};

  i32x4 acc[4][4];
#pragma unroll
  for (int mt = 0; mt < 4; ++mt)
#pragma unroll
    for (int nt = 0; nt < 4; ++nt) acc[mt][nt] = (i32x4){0, 0, 0, 0};

  const int8_t* wnb = wq + nb * 149760;
  const int aoffk = kq * 9232;               // A slot base for this lane
  const int boffk = kq * 1040 + (c << 4);    // B slot/co base for this lane

#define STAGE(CH) do {                                                      \
  const int8_t* wch = wnb + (CH) * 37440;                                   \
  _Pragma("unroll")                                                         \
  for (int i = 0; i < 5; ++i) {                                             \
    if (i < 4 || tid < 256)                                                 \
      gload16(act + srcA[i] + ((CH) << 6), ldsA + dstA[i]);                 \
    if (i < 4 || tid < 292)                                                 \
      gload16(wch + ((tid + (i << 9)) << 4), ldsB + ((tid + (i << 9)) << 4));\
  }                                                                         \
} while (0)

  STAGE(0);
  __syncthreads();  // implicit vmcnt(0): staged data visible

  for (int chunk = 0; chunk < 4; ++chunk) {
    __builtin_amdgcn_s_setprio(1);
#pragma unroll
    for (int tap = 0; tap < 9; ++tap) {
      const int ky = tap / 3, kx = tap % 3;
      // per-lane A pixel addresses for the 4 m-tiles (halo -> zero-px 576)
      const int xa = c + kx - 1;
      const int xb = xa + 16;
      const bool xaok = (unsigned)xa < 32u;
      const bool xbok = xb < 32;
      const int ra = (wid << 1) + ky;
      const int rb = ra + 1;
      const bool raok = (unsigned)(y0 + ra - 1) < 32u;
      const bool rbok = (unsigned)(y0 + rb - 1) < 32u;
      const int ap0 = (raok && xaok) ? (ra << 5) + xa : 576;
      const int ap1 = (raok && xbok) ? (ra << 5) + xb : 576;
      const int ap2 = (rbok && xaok) ? (rb << 5) + xa : 576;
      const int ap3 = (rbok && xbok) ? (rb << 5) + xb : 576;
      // B fragments: 4 x ds_read_b128
      const int bb = tap * 4160 + boffk;
      const i32x4 b0 = *(const i32x4*)(ldsB + bb);
      const i32x4 b1 = *(const i32x4*)(ldsB + bb + 256);
      const i32x4 b2 = *(const i32x4*)(ldsB + bb + 512);
      const i32x4 b3 = *(const i32x4*)(ldsB + bb + 768);
#define DO_MT(M, AP) do {                                                     \
      const i32x4 af = *(const i32x4*)(ldsA + aoffk + ((AP) << 4));           \
      acc[M][0] = __builtin_amdgcn_mfma_i32_16x16x64_i8(af, b0, acc[M][0], 0, 0, 0); \
      acc[M][1] = __builtin_amdgcn_mfma_i32_16x16x64_i8(af, b1, acc[M][1], 0, 0, 0); \
      acc[M][2] = __builtin_amdgcn_mfma_i32_16x16x64_i8(af, b2, acc[M][2], 0, 0, 0); \
      acc[M][3] = __builtin_amdgcn_mfma_i32_16x16x64_i8(af, b3, acc[M][3], 0, 0, 0); \
    } while (0)
      DO_MT(0, ap0);
      DO_MT(1, ap1);
      DO_MT(2, ap2);
      DO_MT(3, ap3);
#undef DO_MT
    }
    __builtin_amdgcn_s_setprio(0);
    if (chunk < 3) {
      __syncthreads();  // all waves done reading this chunk
      STAGE(chunk + 1);
      __syncthreads();  // drain
    }
  }

  // C/D (16x16): col(co) = lane&15, row(m) = (lane>>4)*4 + reg
  const float alpha = alphas[aidx];
  if constexpr (EPI == 0) {
#pragma unroll
    for (int nt = 0; nt < 4; ++nt) {
      const int co = (nb << 6) + (nt << 4) + c;
      const float inv = inv2[co];
      const float ad = add2[co];
#pragma unroll
      for (int mt = 0; mt < 4; ++mt) {
        const int pixb = (mb << 9) + (((wid << 1) + (mt >> 1)) << 5) +
                         ((mt & 1) << 4) + (kq << 2);
#pragma unroll
        for (int j = 0; j < 4; ++j) {
          const float h = alpha * (float)acc[mt][nt][j];
          const float tt = fmaf(h, inv, ad);
          aout[((pixb + j) << 8) + co] = (tt >= 0.f) ? (int8_t)1 : (int8_t)-1;
        }
      }
    }
  } else {
#pragma unroll
    for (int nt = 0; nt < 4; ++nt) {
      const int co = (nb << 6) + (nt << 4) + c;
#pragma unroll
      for (int mt = 0; mt < 4; ++mt) {
        const int pimg = ((mb & 1) << 9) + (((wid << 1) + (mt >> 1)) << 5) +
                         ((mt & 1) << 4) + (kq << 2);
        const int off = (((n << 8) + co) << 10) + pimg;
        const float4 xv = *(const float4*)(xres + off);
        float4 o;
        o.x = xv.x + alpha * (float)acc[mt][nt][0];
        o.y = xv.y + alpha * (float)acc[mt][nt][1];
        o.z = xv.z + alpha * (float)acc[mt][nt][2];
        o.w = xv.w + alpha * (float)acc[mt][nt][3];
        *(float4*)(fout + off) = o;
      }
    }
  }
#undef STAGE
}

extern "C" void kernel_launch(void* const* d_in, const int* in_sizes, int n_in,
                              void* d_out, int out_size, void* d_ws, size_t ws_size,
                              hipStream_t stream) {
  const float* x  = (const float*)d_in[0];
  const float* g1 = (const float*)d_in[1];
  const float* b1 = (const float*)d_in[2];
  const float* m1 = (const float*)d_in[3];
  const float* v1 = (const float*)d_in[4];
  const float* w1 = (const float*)d_in[5];
  const float* g2 = (const float*)d_in[6];
  const float* b2 = (const float*)d_in[7];
  const float* m2 = (const float*)d_in[8];
  const float* v2 = (const float*)d_in[9];
  const float* w2 = (const float*)d_in[10];
  float* out = (float*)d_out;

  char* ws = (char*)d_ws;
  int8_t* a1  = (int8_t*)(ws);                        // 16 MB
  int8_t* a2  = (int8_t*)(ws + 16777216);             // 16 MB
  int8_t* wq1 = (int8_t*)(ws + 33554432);             // 599040 B
  int8_t* wq2 = (int8_t*)(ws + 33554432 + 599040);    // 599040 B
  float* fs = (float*)(ws + 33554432 + 1198080);
  float* pd1    = fs;          // 72 entries
  float* pd2    = fs + 128;    // 72 entries
  float* deltas = fs + 256;
  float* alphas = fs + 260;
  float* psb    = fs + 512;    // ps1[2304], pc1[2304], ps2[2304], pc2[2304]
  float* inv2   = fs + 512 + 9216;
  float* add2   = fs + 512 + 9472;

  hipLaunchKernelGGL(wsum_kernel, dim3(72, 2), dim3(256), 0, stream, w1, w2, fs);
  hipLaunchKernelGGL(delta_kernel, dim3(1), dim3(64), 0, stream, pd1, pd2, deltas);
  hipLaunchKernelGGL(quant_kernel, dim3(2304, 2), dim3(256), 0, stream,
                     w1, w2, deltas, wq1, wq2, psb);
  hipLaunchKernelGGL(alpha_kernel, dim3(1), dim3(256), 0, stream,
                     psb, psb + 2304, psb + 4608, psb + 6912,
                     g2, b2, m2, v2, alphas, inv2, add2);
  hipLaunchKernelGGL(bn_bin_kernel, dim3(16, 8, 64), dim3(256), 0, stream, x, g1, b1, m1, v1, a1);
  hipLaunchKernelGGL((conv3x3_tbn<0>), dim3(512), dim3(512), 0, stream,
                     a1, wq1, alphas, 0, inv2, add2, (const float*)nullptr,
                     a2, (float*)nullptr);
  hipLaunchKernelGGL((conv3x3_tbn<1>), dim3(512), dim3(512), 0, stream,
                     a2, wq2, alphas, 1, (const float*)nullptr, (const float*)nullptr, x,
                     (int8_t*)nullptr, out);
  (void)in_sizes; (void)n_in; (void)out_size; (void)ws_size;
}